// Round 12
// baseline (88.142 us; speedup 1.0000x reference)
//
#include <hip/hip_runtime.h>
#include <stdint.h>

#define BATCH 4
#define NN 4096
#define DD 256
#define TI 128
#define TJ 64
#define JS 2
#define JRANGE (NN / JS)      // 2048
#define NITER (JRANGE / TJ)   // 32

#define VS_OFF 0              // 2 x 32768 B (V_j tile [64][256] bf16, 16B-chunk XOR swizzle)
#define VT_OFF 65536          // 2 x 32768 B (V_j^T tile [256][64] bf16, swizzled)
#define P_OFF  131072         // 2 x 16384 B (P [128][64] bf16, swizzled, double-buffered)
#define LDS_BYTES 163840      // exactly 160 KiB

typedef __attribute__((ext_vector_type(8))) short bf16x8;
typedef __attribute__((ext_vector_type(4))) float f32x4;
typedef __attribute__((ext_vector_type(4))) float f4v;
typedef __attribute__((ext_vector_type(4))) short s4v;
typedef __attribute__((ext_vector_type(8))) short s8v;
typedef __attribute__((ext_vector_type(2))) unsigned int u32x2;

__device__ __forceinline__ short f2bf(float f) {
    uint32_t u = __builtin_bit_cast(uint32_t, f);
    u = (u + 0x7fffu + ((u >> 16) & 1u)) >> 16;
    return (short)u;
}
__device__ __forceinline__ float bf2f(unsigned short u) {
    uint32_t x = ((uint32_t)u) << 16;
    return __builtin_bit_cast(float, x);
}

__device__ __forceinline__ void g2l16(const void* g, void* l) {
    __builtin_amdgcn_global_load_lds((const __attribute__((address_space(1))) void*)g,
                                     (__attribute__((address_space(3))) void*)l, 16, 0, 0);
}

// ---------------- prep: f32 [B][N][D] -> bf16 [B][N][D] and bf16 [B][D][N] (vectorized) ----------------
__global__ __launch_bounds__(256) void prep_k(const float* __restrict__ val,
                                              short* __restrict__ vbf,
                                              short* __restrict__ vt) {
    __shared__ float tile[32][33];
    const int b = blockIdx.z;
    const int d0 = blockIdx.x * 32, n0 = blockIdx.y * 32;
    const int tid = threadIdx.x;
    const int tx = tid & 7, ty = tid >> 3;   // tx: d-chunk of 4, ty: n-row

    f4v v = *(const f4v*)(val + ((size_t)b * NN + n0 + ty) * DD + d0 + tx * 4);
    s4v o;
    o[0] = f2bf(v[0]); o[1] = f2bf(v[1]); o[2] = f2bf(v[2]); o[3] = f2bf(v[3]);
    *(s4v*)(vbf + ((size_t)b * NN + n0 + ty) * DD + d0 + tx * 4) = o;
    tile[ty][tx * 4 + 0] = v[0];
    tile[ty][tx * 4 + 1] = v[1];
    tile[ty][tx * 4 + 2] = v[2];
    tile[ty][tx * 4 + 3] = v[3];
    __syncthreads();

    const int dd = tid >> 3, nc = (tid & 7) * 4;
    s4v w;
#pragma unroll
    for (int j = 0; j < 4; ++j) w[j] = f2bf(tile[nc + j][dd]);
    *(s4v*)(vt + ((size_t)b * DD + d0 + dd) * NN + n0 + nc) = w;
}

// ---------------- main fused kernel (R11 + per-SIMD antiphase S/PV stagger) ----------------
// grid: 256 blocks, 512 threads (8 waves). SIMD k hosts waves k and k+4 ->
// waves 0-3: S(t) then PV(t-1); waves 4-7: PV(t-1) then S(t). Softsign last for all.
__global__ void __launch_bounds__(512, 2) prop_main(const short* __restrict__ vbf,
                                                    const short* __restrict__ vtbf,
                                                    const float* __restrict__ state,
                                                    unsigned short* __restrict__ part,
                                                    float* __restrict__ spart) {
    extern __shared__ char smem[];

    const int bid = blockIdx.x;
    const int js = bid & 1;
    const int rb = (bid >> 1) & 31;
    const int b = bid >> 6;
    const int tid = threadIdx.x;
    const int w = tid >> 6, lane = tid & 63;
    const int g = lane >> 4, c = lane & 15;
    const int ig = w & 3, jh = w >> 2;
    const int wr = w & 1, wd = w >> 1;
    const int r7 = c & 7;
    const int j0base = js * JRANGE;
    const int pvFirst = (w >> 2) & 1;    // antiphase selector: one of each per SIMD

    // 16B-slot byte offsets: ((k*4+g)^r7)<<4 = (k>>1)*128 + (k&1 ? xO : xE)
    const int xE = ((((r7 >> 2) << 2) | (g ^ (r7 & 3))) << 4);
    const int xO = (((((r7 >> 2) ^ 1) << 2) | (g ^ (r7 & 3))) << 4);

    // V_i rows resident in registers (B-operand of S^T)
    bf16x8 Bf[2][8];
    const size_t irowb = (size_t)b * NN + rb * TI + ig * 32;
#pragma unroll
    for (int m = 0; m < 2; ++m)
#pragma unroll
        for (int k = 0; k < 8; ++k)
            Bf[m][k] = *(const bf16x8*)(vbf + ((irowb + m * 16 + c) * DD + k * 32 + g * 8));

    f32x4 accO[4][4];
#pragma unroll
    for (int mt = 0; mt < 4; ++mt)
#pragma unroll
        for (int dt = 0; dt < 4; ++dt)
            accO[mt][dt] = (f32x4){0.f, 0.f, 0.f, 0.f};
    float vsum[2] = {0.f, 0.f};

    auto stageVs = [&](int t, int nb) {
        const int j0 = j0base + t * TJ;
        char* dst = smem + VS_OFF + nb * 32768;
#pragma unroll
        for (int p = 0; p < 4; ++p) {
            int ch0 = p * 512 + w * 64;
            int ch = ch0 + lane;
            int row = ch >> 5, cir = ch & 31;
            g2l16(vbf + ((size_t)(b * NN + j0 + row) * DD + ((cir ^ (row & 7)) * 8)),
                  dst + ch0 * 16);
        }
    };
    auto stageVt = [&](int t, int nb) {
        const int j0 = j0base + t * TJ;
        char* dst = smem + VT_OFF + nb * 32768;
#pragma unroll
        for (int p = 0; p < 4; ++p) {
            int ch0 = p * 512 + w * 64;
            int ch = ch0 + lane;
            int d = ch >> 3, cj = ch & 7;
            g2l16(vtbf + ((size_t)(b * DD + d) * NN + j0 + ((cj ^ (d & 7)) * 8)),
                  dst + ch0 * 16);
        }
    };

    auto pvStep = [&](int slot) {
        const char* paRow = smem + P_OFF + slot * 16384 + (wr * 64 + c) * 128;
        const char* vbRow = smem + VT_OFF + slot * 32768 + (wd * 64 + c) * 128;
        __builtin_amdgcn_s_setprio(1);
#pragma unroll
        for (int kk = 0; kk < 2; ++kk) {
            const int off = kk ? xO : xE;
            bf16x8 pa[4], vb[4];
#pragma unroll
            for (int mt = 0; mt < 4; ++mt) pa[mt] = *(const bf16x8*)(paRow + mt * 2048 + off);
#pragma unroll
            for (int dt = 0; dt < 4; ++dt) vb[dt] = *(const bf16x8*)(vbRow + dt * 2048 + off);
#pragma unroll
            for (int mt = 0; mt < 4; ++mt)
#pragma unroll
                for (int dt = 0; dt < 4; ++dt)
                    accO[mt][dt] = __builtin_amdgcn_mfma_f32_16x16x32_bf16(pa[mt], vb[dt], accO[mt][dt], 0, 0, 0);
        }
        __builtin_amdgcn_s_setprio(0);
    };

    auto sStep = [&](int cur, f32x4 (*accS)[2]) {
#pragma unroll
        for (int jbl = 0; jbl < 2; ++jbl)
#pragma unroll
            for (int m = 0; m < 2; ++m)
                accS[jbl][m] = (f32x4){0.f, 0.f, 0.f, 0.f};
        const char* aRow0 = smem + VS_OFF + cur * 32768 + (jh * 32 + c) * 512;
#pragma unroll
        for (int k = 0; k < 8; ++k) {
            const int off = (k >> 1) * 128 + ((k & 1) ? xO : xE);
            bf16x8 a0 = *(const bf16x8*)(aRow0 + off);
            bf16x8 a1 = *(const bf16x8*)(aRow0 + 8192 + off);
            accS[0][0] = __builtin_amdgcn_mfma_f32_16x16x32_bf16(a0, Bf[0][k], accS[0][0], 0, 0, 0);
            accS[0][1] = __builtin_amdgcn_mfma_f32_16x16x32_bf16(a0, Bf[1][k], accS[0][1], 0, 0, 0);
            accS[1][0] = __builtin_amdgcn_mfma_f32_16x16x32_bf16(a1, Bf[0][k], accS[1][0], 0, 0, 0);
            accS[1][1] = __builtin_amdgcn_mfma_f32_16x16x32_bf16(a1, Bf[1][k], accS[1][1], 0, 0, 0);
        }
    };

    const float* stp = state + b * NN + j0base;

    // prologue: tile 0 into slot 0
    stageVs(0, 0);
    stageVt(0, 0);
    __syncthreads();

    for (int t = 0; t < NITER; ++t) {
        const int cur = t & 1, prv = cur ^ 1;

        // issue next Vs stage (slot prv; old reader finished before last barrier)
        if (t + 1 < NITER) stageVs(t + 1, prv);

        // state prefetch for this tile (L2-resident, broadcast within 16-lane groups)
        f4v sv0 = *(const f4v*)(stp + t * TJ + jh * 32 + g * 4);
        f4v sv1 = *(const f4v*)(stp + t * TJ + jh * 32 + 16 + g * 4);

        f32x4 accS[2][2];
        // ---- antiphase: waves 0-3 do S then PV; waves 4-7 do PV then S ----
        if (pvFirst) {
            if (t > 0) pvStep(prv);
            sStep(cur, accS);
        } else {
            sStep(cur, accS);
            if (t > 0) pvStep(prv);
        }

        // ---- softsign(t) + state-accum + P write via v_cvt_pk_bf16_f32 (RNE) ----
#pragma unroll
        for (int jbl = 0; jbl < 2; ++jbl) {
            f4v sv = jbl ? sv1 : sv0;
#pragma unroll
            for (int m = 0; m < 2; ++m) {
                float e[4];
#pragma unroll
                for (int r = 0; r < 4; ++r) {
                    float s = accS[jbl][m][r];
                    e[r] = s * __builtin_amdgcn_rcpf(1.0f + __builtin_fabsf(s));
                    vsum[m] += e[r] * sv[r];
                }
                u32x2 pk;
                asm("v_cvt_pk_bf16_f32 %0, %1, %2" : "=v"(pk[0]) : "v"(e[0]), "v"(e[1]));
                asm("v_cvt_pk_bf16_f32 %0, %1, %2" : "=v"(pk[1]) : "v"(e[2]), "v"(e[3]));
                int i = ig * 32 + m * 16 + c;
                *(u32x2*)(smem + P_OFF + cur * 16384 + i * 128 +
                          ((jh * 64 + jbl * 32 + g * 8) ^ (r7 << 4))) = pk;
            }
        }

        __syncthreads();   // P[cur] visible; Vs(t+1) + Vt(t+1)-from-prev-iter drained

        if (t + 1 < NITER) stageVt(t + 1, prv);
    }

    // epilogue: PV for the last tile (P[1], Vt[1])
    pvStep((NITER - 1) & 1);

    // ---- delta_val partials (bf16; absmax 8 < 19.44, R7/R9-proven) ----
    {
        unsigned short* po = part + (((size_t)(js * BATCH + b) * NN + rb * TI + wr * 64) * DD) + wd * 64;
#pragma unroll
        for (int mt = 0; mt < 4; ++mt)
#pragma unroll
            for (int dt = 0; dt < 4; ++dt)
#pragma unroll
                for (int r = 0; r < 4; ++r)
                    po[(size_t)(mt * 16 + g * 4 + r) * DD + dt * 16 + c] =
                        (unsigned short)f2bf(accO[mt][dt][r]);
    }

    // ---- delta_state partials (reduce over g via shfl, across jh via LDS) ----
#pragma unroll
    for (int m = 0; m < 2; ++m) {
        vsum[m] += __shfl_xor(vsum[m], 16);
        vsum[m] += __shfl_xor(vsum[m], 32);
    }
    float* Xf = (float*)(smem + P_OFF);   // P[0] region is dead now
    __syncthreads();
    if (jh == 1 && lane < 16) {
        Xf[(ig * 2 + 0) * 16 + lane] = vsum[0];
        Xf[(ig * 2 + 1) * 16 + lane] = vsum[1];
    }
    __syncthreads();
    if (jh == 0 && lane < 16) {
        size_t sb = ((size_t)js * BATCH + b) * NN + rb * TI + ig * 32;
#pragma unroll
        for (int m = 0; m < 2; ++m)
            spart[sb + m * 16 + lane] = vsum[m] + Xf[(ig * 2 + m) * 16 + lane];
    }
}

// ---------------- final reduce (vectorized): out[b,i,0:256] = p0+p1 ; out[b,i,256] = s0+s1 ----------------
__global__ __launch_bounds__(256) void reduce2_k(const unsigned short* __restrict__ part,
                                                 const float* __restrict__ spart,
                                                 float* __restrict__ out) {
    const int tid = threadIdx.x;
    const int row = blockIdx.x * 8 + (tid >> 5);    // 8 rows/block, 16384 rows total
    const int c8 = (tid & 31) * 8;
    const size_t PS = (size_t)BATCH * NN * DD;

    s8v a = *(const s8v*)(part + (size_t)row * DD + c8);
    s8v bb = *(const s8v*)(part + PS + (size_t)row * DD + c8);
    float* po = out + (size_t)row * 257 + c8;
#pragma unroll
    for (int j = 0; j < 8; ++j)
        po[j] = bf2f((unsigned short)a[j]) + bf2f((unsigned short)bb[j]);
    if ((tid & 31) == 31) {
        const size_t SS = (size_t)BATCH * NN;
        out[(size_t)row * 257 + 256] = spart[row] + spart[SS + row];
    }
}

extern "C" void kernel_launch(void* const* d_in, const int* in_sizes, int n_in,
                              void* d_out, int out_size, void* d_ws, size_t ws_size,
                              hipStream_t stream) {
    const float* val = (const float*)d_in[0];
    const float* state = (const float*)d_in[1];
    float* out = (float*)d_out;

    const size_t bf_bytes = (size_t)BATCH * NN * DD * 2;            // 8 MiB
    const size_t part_bytes = (size_t)JS * BATCH * NN * DD * 2;     // 16 MiB (bf16)
    const size_t spart_bytes = (size_t)JS * BATCH * NN * 4;         // 128 KiB
    short* vbf = (short*)d_ws;
    short* vtbf = (short*)((char*)d_ws + bf_bytes);
    unsigned short* part = (unsigned short*)((char*)d_ws + 2 * bf_bytes);
    float* spart = (float*)((char*)d_ws + 2 * bf_bytes + part_bytes);
    if (ws_size < 2 * bf_bytes + part_bytes + spart_bytes) return;

    hipFuncSetAttribute((const void*)prop_main, hipFuncAttributeMaxDynamicSharedMemorySize, LDS_BYTES);

    prep_k<<<dim3(DD / 32, NN / 32, BATCH), 256, 0, stream>>>(val, vbf, vtbf);
    prop_main<<<BATCH * (NN / TI) * JS, 512, LDS_BYTES, stream>>>(vbf, vtbf, state, part, spart);
    reduce2_k<<<(BATCH * NN) / 8, 256, 0, stream>>>(part, spart, out);
}

// Round 13
// 87.372 us; speedup vs baseline: 1.0088x; 1.0088x over previous
//
#include <hip/hip_runtime.h>
#include <stdint.h>

#define BATCH 4
#define NN 4096
#define DD 256
#define TI 128
#define TJ 64
#define JS 2
#define JRANGE (NN / JS)      // 2048
#define NITER (JRANGE / TJ)   // 32

#define VS_OFF 0              // 2 x 32768 B (V_j tile [64][256] bf16, 16B-chunk XOR swizzle)
#define VT_OFF 65536          // 2 x 32768 B (V_j^T tile [256][64] bf16, swizzled)
#define P_OFF  131072         // 2 x 16384 B (P [128][64] bf16, swizzled, double-buffered)
#define LDS_BYTES 163840      // exactly 160 KiB

typedef __attribute__((ext_vector_type(8))) short bf16x8;
typedef __attribute__((ext_vector_type(4))) float f32x4;
typedef __attribute__((ext_vector_type(4))) float f4v;
typedef __attribute__((ext_vector_type(4))) short s4v;
typedef __attribute__((ext_vector_type(8))) short s8v;
typedef __attribute__((ext_vector_type(2))) unsigned int u32x2;

__device__ __forceinline__ short f2bf(float f) {
    uint32_t u = __builtin_bit_cast(uint32_t, f);
    u = (u + 0x7fffu + ((u >> 16) & 1u)) >> 16;
    return (short)u;
}
__device__ __forceinline__ float bf2f(unsigned short u) {
    uint32_t x = ((uint32_t)u) << 16;
    return __builtin_bit_cast(float, x);
}

__device__ __forceinline__ void g2l16(const void* g, void* l) {
    __builtin_amdgcn_global_load_lds((const __attribute__((address_space(1))) void*)g,
                                     (__attribute__((address_space(3))) void*)l, 16, 0, 0);
}

// ---------------- prep: f32 [B][N][D] -> bf16 [B][N][D] and bf16 [B][D][N] (vectorized) ----------------
__global__ __launch_bounds__(256) void prep_k(const float* __restrict__ val,
                                              short* __restrict__ vbf,
                                              short* __restrict__ vt) {
    __shared__ float tile[32][33];
    const int b = blockIdx.z;
    const int d0 = blockIdx.x * 32, n0 = blockIdx.y * 32;
    const int tid = threadIdx.x;
    const int tx = tid & 7, ty = tid >> 3;   // tx: d-chunk of 4, ty: n-row

    f4v v = *(const f4v*)(val + ((size_t)b * NN + n0 + ty) * DD + d0 + tx * 4);
    s4v o;
    o[0] = f2bf(v[0]); o[1] = f2bf(v[1]); o[2] = f2bf(v[2]); o[3] = f2bf(v[3]);
    *(s4v*)(vbf + ((size_t)b * NN + n0 + ty) * DD + d0 + tx * 4) = o;
    tile[ty][tx * 4 + 0] = v[0];
    tile[ty][tx * 4 + 1] = v[1];
    tile[ty][tx * 4 + 2] = v[2];
    tile[ty][tx * 4 + 3] = v[3];
    __syncthreads();

    const int dd = tid >> 3, nc = (tid & 7) * 4;
    s4v w;
#pragma unroll
    for (int j = 0; j < 4; ++j) w[j] = f2bf(tile[nc + j][dd]);
    *(s4v*)(vt + ((size_t)b * DD + d0 + dd) * NN + n0 + nc) = w;
}

// ---------------- main fused kernel (R11 configuration — measured optimum) ----------------
// grid: 256 blocks, 512 threads (8 waves)
// iter t = { stage Vs(t+1) | S(t) | PV(t-1) | softsign(t)->P[t&1] } bar { stage Vt(t+1) }
__global__ void __launch_bounds__(512, 2) prop_main(const short* __restrict__ vbf,
                                                    const short* __restrict__ vtbf,
                                                    const float* __restrict__ state,
                                                    unsigned short* __restrict__ part,
                                                    float* __restrict__ spart) {
    extern __shared__ char smem[];

    const int bid = blockIdx.x;
    const int js = bid & 1;
    const int rb = (bid >> 1) & 31;
    const int b = bid >> 6;
    const int tid = threadIdx.x;
    const int w = tid >> 6, lane = tid & 63;
    const int g = lane >> 4, c = lane & 15;
    const int ig = w & 3, jh = w >> 2;
    const int wr = w & 1, wd = w >> 1;
    const int r7 = c & 7;
    const int j0base = js * JRANGE;

    // 16B-slot byte offsets: ((k*4+g)^r7)<<4 = (k>>1)*128 + (k&1 ? xO : xE)
    const int xE = ((((r7 >> 2) << 2) | (g ^ (r7 & 3))) << 4);
    const int xO = (((((r7 >> 2) ^ 1) << 2) | (g ^ (r7 & 3))) << 4);

    // V_i rows resident in registers (B-operand of S^T)
    bf16x8 Bf[2][8];
    const size_t irowb = (size_t)b * NN + rb * TI + ig * 32;
#pragma unroll
    for (int m = 0; m < 2; ++m)
#pragma unroll
        for (int k = 0; k < 8; ++k)
            Bf[m][k] = *(const bf16x8*)(vbf + ((irowb + m * 16 + c) * DD + k * 32 + g * 8));

    f32x4 accO[4][4];
#pragma unroll
    for (int mt = 0; mt < 4; ++mt)
#pragma unroll
        for (int dt = 0; dt < 4; ++dt)
            accO[mt][dt] = (f32x4){0.f, 0.f, 0.f, 0.f};
    float vsum[2] = {0.f, 0.f};

    auto stageVs = [&](int t, int nb) {
        const int j0 = j0base + t * TJ;
        char* dst = smem + VS_OFF + nb * 32768;
#pragma unroll
        for (int p = 0; p < 4; ++p) {
            int ch0 = p * 512 + w * 64;
            int ch = ch0 + lane;
            int row = ch >> 5, cir = ch & 31;
            g2l16(vbf + ((size_t)(b * NN + j0 + row) * DD + ((cir ^ (row & 7)) * 8)),
                  dst + ch0 * 16);
        }
    };
    auto stageVt = [&](int t, int nb) {
        const int j0 = j0base + t * TJ;
        char* dst = smem + VT_OFF + nb * 32768;
#pragma unroll
        for (int p = 0; p < 4; ++p) {
            int ch0 = p * 512 + w * 64;
            int ch = ch0 + lane;
            int d = ch >> 3, cj = ch & 7;
            g2l16(vtbf + ((size_t)(b * DD + d) * NN + j0 + ((cj ^ (d & 7)) * 8)),
                  dst + ch0 * 16);
        }
    };

    auto pvStep = [&](int slot) {
        const char* paRow = smem + P_OFF + slot * 16384 + (wr * 64 + c) * 128;
        const char* vbRow = smem + VT_OFF + slot * 32768 + (wd * 64 + c) * 128;
        __builtin_amdgcn_s_setprio(1);
#pragma unroll
        for (int kk = 0; kk < 2; ++kk) {
            const int off = kk ? xO : xE;
            bf16x8 pa[4], vb[4];
#pragma unroll
            for (int mt = 0; mt < 4; ++mt) pa[mt] = *(const bf16x8*)(paRow + mt * 2048 + off);
#pragma unroll
            for (int dt = 0; dt < 4; ++dt) vb[dt] = *(const bf16x8*)(vbRow + dt * 2048 + off);
#pragma unroll
            for (int mt = 0; mt < 4; ++mt)
#pragma unroll
                for (int dt = 0; dt < 4; ++dt)
                    accO[mt][dt] = __builtin_amdgcn_mfma_f32_16x16x32_bf16(pa[mt], vb[dt], accO[mt][dt], 0, 0, 0);
        }
        __builtin_amdgcn_s_setprio(0);
    };

    const float* stp = state + b * NN + j0base;

    // prologue: tile 0 into slot 0
    stageVs(0, 0);
    stageVt(0, 0);
    __syncthreads();

    for (int t = 0; t < NITER; ++t) {
        const int cur = t & 1, prv = cur ^ 1;

        // A: issue next Vs stage (slot prv == (t+1)&1; its old reader S(t-1) finished before last barrier)
        if (t + 1 < NITER) stageVs(t + 1, prv);

        // state prefetch for this tile (L2-resident, broadcast within 16-lane groups)
        f4v sv0 = *(const f4v*)(stp + t * TJ + jh * 32 + g * 4);
        f4v sv1 = *(const f4v*)(stp + t * TJ + jh * 32 + 16 + g * 4);

        // ---- S(t): S^T = V_j . V_i^T  (A = V_j from Vs[cur], B = V_i regs) ----
        f32x4 accS[2][2];
#pragma unroll
        for (int jbl = 0; jbl < 2; ++jbl)
#pragma unroll
            for (int m = 0; m < 2; ++m)
                accS[jbl][m] = (f32x4){0.f, 0.f, 0.f, 0.f};

        const char* aRow0 = smem + VS_OFF + cur * 32768 + (jh * 32 + c) * 512;
#pragma unroll
        for (int k = 0; k < 8; ++k) {
            const int off = (k >> 1) * 128 + ((k & 1) ? xO : xE);
            bf16x8 a0 = *(const bf16x8*)(aRow0 + off);
            bf16x8 a1 = *(const bf16x8*)(aRow0 + 8192 + off);
            accS[0][0] = __builtin_amdgcn_mfma_f32_16x16x32_bf16(a0, Bf[0][k], accS[0][0], 0, 0, 0);
            accS[0][1] = __builtin_amdgcn_mfma_f32_16x16x32_bf16(a0, Bf[1][k], accS[0][1], 0, 0, 0);
            accS[1][0] = __builtin_amdgcn_mfma_f32_16x16x32_bf16(a1, Bf[0][k], accS[1][0], 0, 0, 0);
            accS[1][1] = __builtin_amdgcn_mfma_f32_16x16x32_bf16(a1, Bf[1][k], accS[1][1], 0, 0, 0);
        }

        // ---- PV(t-1): O += P . V_j  (reads P[prv], Vt[prv]; independent of S(t)) ----
        if (t > 0) pvStep(prv);

        // ---- softsign(t) + state-accum + P write via v_cvt_pk_bf16_f32 (RNE, = old f2bf) ----
#pragma unroll
        for (int jbl = 0; jbl < 2; ++jbl) {
            f4v sv = jbl ? sv1 : sv0;
#pragma unroll
            for (int m = 0; m < 2; ++m) {
                float e[4];
#pragma unroll
                for (int r = 0; r < 4; ++r) {
                    float s = accS[jbl][m][r];
                    e[r] = s * __builtin_amdgcn_rcpf(1.0f + __builtin_fabsf(s));
                    vsum[m] += e[r] * sv[r];
                }
                u32x2 pk;
                asm("v_cvt_pk_bf16_f32 %0, %1, %2" : "=v"(pk[0]) : "v"(e[0]), "v"(e[1]));
                asm("v_cvt_pk_bf16_f32 %0, %1, %2" : "=v"(pk[1]) : "v"(e[2]), "v"(e[3]));
                int i = ig * 32 + m * 16 + c;
                *(u32x2*)(smem + P_OFF + cur * 16384 + i * 128 +
                          ((jh * 64 + jbl * 32 + g * 8) ^ (r7 << 4))) = pk;
            }
        }

        __syncthreads();   // P[cur] visible; Vs(t+1) + Vt(t+1)-from-prev-iter drained

        // D: issue next Vt stage (slot prv; drains at next iter's barrier, consumed the iter after)
        if (t + 1 < NITER) stageVt(t + 1, prv);
    }

    // epilogue: PV for the last tile (P[1], Vt[1])
    pvStep((NITER - 1) & 1);

    // ---- delta_val partials (bf16; absmax 8 < 19.44, R7/R9-proven) ----
    {
        unsigned short* po = part + (((size_t)(js * BATCH + b) * NN + rb * TI + wr * 64) * DD) + wd * 64;
#pragma unroll
        for (int mt = 0; mt < 4; ++mt)
#pragma unroll
            for (int dt = 0; dt < 4; ++dt)
#pragma unroll
                for (int r = 0; r < 4; ++r)
                    po[(size_t)(mt * 16 + g * 4 + r) * DD + dt * 16 + c] =
                        (unsigned short)f2bf(accO[mt][dt][r]);
    }

    // ---- delta_state partials (reduce over g via shfl, across jh via LDS) ----
#pragma unroll
    for (int m = 0; m < 2; ++m) {
        vsum[m] += __shfl_xor(vsum[m], 16);
        vsum[m] += __shfl_xor(vsum[m], 32);
    }
    float* Xf = (float*)(smem + P_OFF);   // P[0] region is dead now
    __syncthreads();
    if (jh == 1 && lane < 16) {
        Xf[(ig * 2 + 0) * 16 + lane] = vsum[0];
        Xf[(ig * 2 + 1) * 16 + lane] = vsum[1];
    }
    __syncthreads();
    if (jh == 0 && lane < 16) {
        size_t sb = ((size_t)js * BATCH + b) * NN + rb * TI + ig * 32;
#pragma unroll
        for (int m = 0; m < 2; ++m)
            spart[sb + m * 16 + lane] = vsum[m] + Xf[(ig * 2 + m) * 16 + lane];
    }
}

// ---------------- final reduce (vectorized): out[b,i,0:256] = p0+p1 ; out[b,i,256] = s0+s1 ----------------
__global__ __launch_bounds__(256) void reduce2_k(const unsigned short* __restrict__ part,
                                                 const float* __restrict__ spart,
                                                 float* __restrict__ out) {
    const int tid = threadIdx.x;
    const int row = blockIdx.x * 8 + (tid >> 5);    // 8 rows/block, 16384 rows total
    const int c8 = (tid & 31) * 8;
    const size_t PS = (size_t)BATCH * NN * DD;

    s8v a = *(const s8v*)(part + (size_t)row * DD + c8);
    s8v bb = *(const s8v*)(part + PS + (size_t)row * DD + c8);
    float* po = out + (size_t)row * 257 + c8;
#pragma unroll
    for (int j = 0; j < 8; ++j)
        po[j] = bf2f((unsigned short)a[j]) + bf2f((unsigned short)bb[j]);
    if ((tid & 31) == 31) {
        const size_t SS = (size_t)BATCH * NN;
        out[(size_t)row * 257 + 256] = spart[row] + spart[SS + row];
    }
}

extern "C" void kernel_launch(void* const* d_in, const int* in_sizes, int n_in,
                              void* d_out, int out_size, void* d_ws, size_t ws_size,
                              hipStream_t stream) {
    const float* val = (const float*)d_in[0];
    const float* state = (const float*)d_in[1];
    float* out = (float*)d_out;

    const size_t bf_bytes = (size_t)BATCH * NN * DD * 2;            // 8 MiB
    const size_t part_bytes = (size_t)JS * BATCH * NN * DD * 2;     // 16 MiB (bf16)
    const size_t spart_bytes = (size_t)JS * BATCH * NN * 4;         // 128 KiB
    short* vbf = (short*)d_ws;
    short* vtbf = (short*)((char*)d_ws + bf_bytes);
    unsigned short* part = (unsigned short*)((char*)d_ws + 2 * bf_bytes);
    float* spart = (float*)((char*)d_ws + 2 * bf_bytes + part_bytes);
    if (ws_size < 2 * bf_bytes + part_bytes + spart_bytes) return;

    hipFuncSetAttribute((const void*)prop_main, hipFuncAttributeMaxDynamicSharedMemorySize, LDS_BYTES);

    prep_k<<<dim3(DD / 32, NN / 32, BATCH), 256, 0, stream>>>(val, vbf, vtbf);
    prop_main<<<BATCH * (NN / TI) * JS, 512, LDS_BYTES, stream>>>(vbf, vtbf, state, part, spart);
    reduce2_k<<<(BATCH * NN) / 8, 256, 0, stream>>>(part, spart, out);
}